// Round 8
// baseline (181.296 us; speedup 1.0000x reference)
//
#include <hip/hip_runtime.h>
#include <math.h>

#define NQ   8192      // N queries per batch
#define NP   8192      // M points per batch
#define NF   128       // feature dim
#define NOUT 512       // output dim
#define NB   2         // batches
#define KNN  10
#define BNQ  (NB*NQ)   // 16384 total queries
#define QW   4         // queries per wave

typedef unsigned long long u64;

__device__ __forceinline__ u64 shfl64(u64 v, int src) {
  unsigned lo = (unsigned)__shfl((int)(unsigned)(v & 0xffffffffull), src, 64);
  unsigned hi = (unsigned)__shfl((int)(unsigned)(v >> 32), src, 64);
  return ((u64)hi << 32) | lo;
}
__device__ __forceinline__ u64 shflup64(u64 v) {
  unsigned lo = (unsigned)__shfl_up((int)(unsigned)(v & 0xffffffffull), 1, 64);
  unsigned hi = (unsigned)__shfl_up((int)(unsigned)(v >> 32), 1, 64);
  return ((u64)hi << 32) | lo;
}

// Shifted distance for SELECTION: d2' = p2 - 2 q.p (3 fma). True d2 = d2'+q2.
__device__ __forceinline__ float dist2s(float m2x, float m2y, float m2z,
                                        float4 p) {
  return fmaf(m2x, p.x, fmaf(m2y, p.y, fmaf(m2z, p.z, p.w)));
}

// Monotone f32->u32 bit map: mono(a) < mono(b) (unsigned) <=> a < b (float).
__device__ __forceinline__ unsigned fmono(float f) {
  unsigned u = __float_as_uint(f);
  return u ^ ((unsigned)((int)u >> 31) | 0x80000000u);
}

// nextafter(f, +inf) for finite f (incl. negatives, -0). +INF -> NaN, which
// is harmless where used (fminf(x, NaN) == x).
__device__ __forceinline__ float nextupf(float f) {
  unsigned u = __float_as_uint(f);
  unsigned n = (u & 0x80000000u) ? ((u == 0x80000000u) ? 1u : u - 1u) : u + 1u;
  return __uint_as_float(n);
}

__device__ __forceinline__ float wmin64f(float v) {
#pragma unroll
  for (int off = 1; off < 64; off <<= 1)
    v = fminf(v, __shfl_xor(v, off, 64));
  return v;   // broadcast min across all 64 lanes
}

// Verified distributed sorted-insert (lanes 0..9 hold top-10 as u64 keys
// (mono(d2')<<32)|idx). Per-lane candidate (d2, idxv); processing order is
// arbitrary: the working threshold tracks nextup(dl[9]) so value-ties enter
// and the exact u64 key compare resolves them (a non-qualifying tie inserts
// past slot 9 = no-op). Terminates: each iteration NaN-retires one lane.
__device__ __forceinline__ void insert_loop(float d2, int idxv, int lane,
                                            u64& lst, float& dlv, float& th) {
  for (;;) {
    u64 mask = __ballot(d2 < th);
    if (!mask) break;
    int src = __builtin_ctzll(mask);
    float cd = __uint_as_float(
        (unsigned)__builtin_amdgcn_readlane(__float_as_int(d2), src));
    int  ci = __builtin_amdgcn_readlane(idxv, src);
    u64 kk = ((u64)fmono(cd) << 32) | (unsigned)ci;
    u64   prev  = shflup64(lst);
    float prevd = __shfl(dlv, lane - 1, 64);
    bool mylt = lst < kk;
    bool pins = (lane == 0) || (prev < kk);
    lst = mylt ? lst : (pins ? kk : prev);
    dlv = mylt ? dlv : (pins ? cd : prevd);
    float d9 = __uint_as_float(
        (unsigned)__builtin_amdgcn_readlane(__float_as_int(dlv), 9));
    th = fminf(th, nextupf(d9));
    if (lane == src) d2 = __builtin_nanf("");
  }
}

// ---------------------------------------------------------------------------
// Prep: pack points as (x,y,z,|p|^2) and transpose W[512][128] -> Wt[128][512]
// ---------------------------------------------------------------------------
__global__ __launch_bounds__(256) void prep_kernel(
    const float* __restrict__ gpcd, const float* __restrict__ W,
    float4* __restrict__ pts4, float* __restrict__ Wt)
{
  int tid = blockIdx.x * 256 + threadIdx.x;   // 0..65535
  if (tid < NB * NP) {
    const float* p = gpcd + (size_t)tid * 3;
    float x = p[0], y = p[1], z = p[2];
    float p2 = x * x + y * y + z * z;
    pts4[tid] = make_float4(x, y, z, p2);
  }
  int o = tid >> 7, f = tid & 127;
  Wt[(size_t)f * NOUT + o] = W[tid];
}

// ---------------------------------------------------------------------------
// Stage A+B: ONE scan. Per lane per query keep (m1,i1)=best, (m2,i2)=2nd,
// m3=3rd-best value (certificate). Branch-free 13-VALU update per point.
// Selection: tau knockout on m1 -> theta; verified insert over the 64 m1
// then 64 m2 candidates (~15 entries). Exactness certificate: a true top-10
// member can be missing only if its lane held >=3 of the top-10, which
// implies that lane's m3 <= final dl[9] -> exact full rescan (rare).
// ---------------------------------------------------------------------------
__global__ __launch_bounds__(256) void knn_interp_kernel(
    const float* __restrict__ geometry, const float4* __restrict__ pts4,
    const float* __restrict__ features, float* __restrict__ At)
{
  const int lane = threadIdx.x & 63;
  const int wave = (blockIdx.x << 2) | (threadIdx.x >> 6);
  const int q0   = wave * QW;           // QW consecutive queries (same batch)
  const int b    = q0 >> 13;            // q0 / 8192
  const float4* __restrict__ P = pts4 + ((size_t)b << 13);

  float c2x[QW], c2y[QW], c2z[QW], q2[QW];
#pragma unroll
  for (int j = 0; j < QW; ++j) {
    const float* g = geometry + (size_t)(q0 + j) * 3;
    float x = g[0], y = g[1], z = g[2];
    q2[j]  = x * x + y * y + z * z;
    c2x[j] = -2.0f * x; c2y[j] = -2.0f * y; c2z[j] = -2.0f * z;
  }

  float m1[QW], m2v[QW], m3[QW];
  int   i1[QW], i2[QW];
#pragma unroll
  for (int j = 0; j < QW; ++j) {
    m1[j] = INFINITY; m2v[j] = INFINITY; m3[j] = INFINITY;
    i1[j] = 0; i2[j] = 0;
  }

  // ---- single scan: streaming per-lane top-3 (values) / top-2 (indices) ----
  for (int t = 0; t < NP / 64; ++t) {
    const float4 p = P[(t << 6) | lane];
    const int  idx = (t << 6) | lane;
#pragma unroll
    for (int j = 0; j < QW; ++j) {
      float d  = dist2s(c2x[j], c2y[j], c2z[j], p);
      bool  c1 = d < m1[j];
      bool  c2 = d < m2v[j];
      m3[j]  = fminf(m3[j], fmaxf(d, m2v[j]));
      i2[j]  = c2 ? (c1 ? i1[j] : idx) : i2[j];
      m2v[j] = fminf(m2v[j], fmaxf(d, m1[j]));
      i1[j]  = c1 ? idx : i1[j];
      m1[j]  = fminf(m1[j], d);
    }
  }

  u64   list[QW];
  float dl[QW];

  // ---- selection per query ----
#pragma unroll
  for (int j = 0; j < QW; ++j) {
    // tau = 10th-smallest lane-min (knockout, verified)
    float lm  = m1[j];
    float tau = 0.0f;
#pragma unroll
    for (int r = 0; r < KNN; ++r) {
      tau = wmin64f(lm);
      u64 mk = __ballot(lm == tau);
      int w  = __builtin_ctzll(mk);
      if (lane == w) lm = INFINITY;
    }
    float th = nextupf(tau);

    list[j] = 0xFFFFFFFFFFFFFFFFull;    // (mono(+inf-ish) max key)
    dl[j]   = INFINITY;
    insert_loop(m1[j],  i1[j], lane, list[j], dl[j], th);
    insert_loop(m2v[j], i2[j], lane, list[j], dl[j], th);

    // exactness certificate; rare exact rescan
    float th_v = __uint_as_float(
        (unsigned)__builtin_amdgcn_readlane(__float_as_int(dl[j]), 9));
    if (__ballot(m3[j] <= th_v)) {
      list[j] = 0xFFFFFFFFFFFFFFFFull;
      dl[j]   = INFINITY;
      float th2 = nextupf(th_v);
      for (int t = 0; t < NP / 64; ++t) {
        const float4 p = P[(t << 6) | lane];
        float d = dist2s(c2x[j], c2y[j], c2z[j], p);
        insert_loop(d, (t << 6) | lane, lane, list[j], dl[j], th2);
      }
    }
  }

  // ---- weights + feature interpolation ----
  const float* __restrict__ F = features + (size_t)b * NP * NF;
#pragma unroll
  for (int j = 0; j < QW; ++j) {
    float td2 = fmaxf(dl[j] + q2[j], 0.0f);       // back to true d2, clamped
    float w   = 1.0f / (sqrtf(td2) + 1e-8f);      // meaningful on lanes 0..9
    float wsum = 0.0f;
#pragma unroll
    for (int jj = 0; jj < KNN; ++jj) wsum += __shfl(w, jj, 64);

    float a0 = 0.0f, a1 = 0.0f;
#pragma unroll
    for (int jj = 0; jj < KNN; ++jj) {
      float wj = __shfl(w, jj, 64) / wsum;
      int  mi  = (int)(unsigned)(shfl64(list[j], jj) & 0xffffffffull);
      const float2 f2 = *(const float2*)(F + (size_t)mi * NF + (lane << 1));
      a0 = fmaf(wj, f2.x, a0);
      a1 = fmaf(wj, f2.y, a1);
    }
    At[(size_t)(lane << 1) * BNQ + (q0 + j)]       = a0;
    At[(size_t)((lane << 1) + 1) * BNQ + (q0 + j)] = a1;
  }
}

// ---------------------------------------------------------------------------
// Stage C: out[q][o] = sum_f At[f][q] * Wt[f][o] + bias[o]
// LDS-tiled: 64x64 block tile, KC=64 two-chunk, 4x4 per thread.
// ---------------------------------------------------------------------------
#define PKC  64
#define PLD  68

__global__ __launch_bounds__(256) void proj_kernel(
    const float* __restrict__ At, const float* __restrict__ Wt,
    const float* __restrict__ bias, float* __restrict__ out)
{
  __shared__ __align__(16) float lds_a[PKC][PLD];
  __shared__ __align__(16) float lds_b[PKC][PLD];

  const int mt = blockIdx.x & 255;
  const int ot = blockIdx.x >> 8;
  const int tx = threadIdx.x & 15;
  const int ty = threadIdx.x >> 4;
  const int m0 = mt << 6;
  const int o0 = ot << 6;

  const int lr = threadIdx.x >> 4;
  const int lc = (threadIdx.x & 15) << 2;

  float acc[4][4];
#pragma unroll
  for (int i = 0; i < 4; ++i)
#pragma unroll
    for (int jj = 0; jj < 4; ++jj) acc[i][jj] = 0.0f;

#pragma unroll
  for (int kc = 0; kc < NF / PKC; ++kc) {
    const int k0 = kc * PKC;
#pragma unroll
    for (int rp = 0; rp < 4; ++rp) {
      const int r = (rp << 4) + lr;
      const float4 a4 = *(const float4*)(At + (size_t)(k0 + r) * BNQ  + m0 + lc);
      const float4 b4 = *(const float4*)(Wt + (size_t)(k0 + r) * NOUT + o0 + lc);
      *(float4*)(&lds_a[r][lc]) = a4;
      *(float4*)(&lds_b[r][lc]) = b4;
    }
    __syncthreads();
#pragma unroll 8
    for (int k = 0; k < PKC; ++k) {
      const float4 a  = *(const float4*)(&lds_a[k][ty << 2]);
      const float4 bv = *(const float4*)(&lds_b[k][tx << 2]);
      float av[4] = {a.x, a.y, a.z, a.w};
      float bw[4] = {bv.x, bv.y, bv.z, bv.w};
#pragma unroll
      for (int i = 0; i < 4; ++i)
#pragma unroll
        for (int jj = 0; jj < 4; ++jj)
          acc[i][jj] = fmaf(av[i], bw[jj], acc[i][jj]);
    }
    __syncthreads();
  }

  const float4 bb = *(const float4*)(bias + o0 + (tx << 2));
  float bias4[4] = {bb.x, bb.y, bb.z, bb.w};
#pragma unroll
  for (int i = 0; i < 4; ++i) {
    float4 r;
    r.x = acc[i][0] + bias4[0];
    r.y = acc[i][1] + bias4[1];
    r.z = acc[i][2] + bias4[2];
    r.w = acc[i][3] + bias4[3];
    *(float4*)(out + (size_t)(m0 + (ty << 2) + i) * NOUT + o0 + (tx << 2)) = r;
  }
}

// ---------------------------------------------------------------------------
extern "C" void kernel_launch(void* const* d_in, const int* in_sizes, int n_in,
                              void* d_out, int out_size, void* d_ws, size_t ws_size,
                              hipStream_t stream) {
  const float* geometry = (const float*)d_in[0];   // [2,8192,3]
  const float* gpcd     = (const float*)d_in[1];   // [2,8192,3]
  const float* features = (const float*)d_in[2];   // [2,8192,128]
  const float* W        = (const float*)d_in[3];   // [512,128]
  const float* bias     = (const float*)d_in[4];   // [512]
  float* out = (float*)d_out;

  char*   ws   = (char*)d_ws;
  float*  At   = (float*)ws;                              // 128*16384 f32 = 8 MiB
  float4* pts4 = (float4*)(ws + (size_t)NF * BNQ * 4);    // 16384 * 16 B
  float*  Wt   = (float*)(ws + (size_t)NF * BNQ * 4 + (size_t)NB * NP * 16);

  prep_kernel<<<256, 256, 0, stream>>>(gpcd, W, pts4, Wt);
  knn_interp_kernel<<<BNQ / (QW * 4), 256, 0, stream>>>(geometry, pts4, features, At);
  proj_kernel<<<(BNQ / 64) * (NOUT / 64), 256, 0, stream>>>(At, Wt, bias, out);
}

// Round 9
// 113.951 us; speedup vs baseline: 1.5910x; 1.5910x over previous
//
#include <hip/hip_runtime.h>
#include <math.h>

#define NQ   8192      // N queries per batch
#define NP   8192      // M points per batch
#define NF   128       // feature dim
#define NOUT 512       // output dim
#define NB   2         // batches
#define KNN  10
#define BNQ  (NB*NQ)   // 16384 total queries
#define QW   4         // queries per wave

typedef unsigned long long u64;
typedef unsigned short ushort_t;
typedef __attribute__((ext_vector_type(8))) short bf16x8;
typedef __attribute__((ext_vector_type(4))) float f32x4;

__device__ __forceinline__ u64 shfl64(u64 v, int src) {
  unsigned lo = (unsigned)__shfl((int)(unsigned)(v & 0xffffffffull), src, 64);
  unsigned hi = (unsigned)__shfl((int)(unsigned)(v >> 32), src, 64);
  return ((u64)hi << 32) | lo;
}
__device__ __forceinline__ u64 shflup64(u64 v) {
  unsigned lo = (unsigned)__shfl_up((int)(unsigned)(v & 0xffffffffull), 1, 64);
  unsigned hi = (unsigned)__shfl_up((int)(unsigned)(v >> 32), 1, 64);
  return ((u64)hi << 32) | lo;
}

// d2 = ((q2+p2) + (-2qz)*pz) + (-2qy)*py + (-2qx)*px  (3 fma + 1 add), no clamp
__device__ __forceinline__ float dist2m(float m2x, float m2y, float m2z,
                                        float q2c, float4 p) {
  return fmaf(m2x, p.x, fmaf(m2y, p.y, fmaf(m2z, p.z, q2c + p.w)));
}

__device__ __forceinline__ float wmin64f(float v) {
#pragma unroll
  for (int off = 1; off < 64; off <<= 1)
    v = fminf(v, __shfl_xor(v, off, 64));
  return v;   // broadcast min across all 64 lanes
}

// round-to-nearest-even f32 -> bf16
__device__ __forceinline__ ushort_t f2bf(float x) {
  unsigned u = __float_as_uint(x);
  return (ushort_t)((u + 0x7FFFu + ((u >> 16) & 1u)) >> 16);
}

// ---------------------------------------------------------------------------
// Prep: pack points as (x,y,z,|p|^2); convert W[512][128] -> bf16 Wb[512][128]
// ---------------------------------------------------------------------------
__global__ __launch_bounds__(256) void prep_kernel(
    const float* __restrict__ gpcd, const float* __restrict__ W,
    float4* __restrict__ pts4, ushort_t* __restrict__ Wb)
{
  int tid = blockIdx.x * 256 + threadIdx.x;   // 0..65535
  if (tid < NB * NP) {
    const float* p = gpcd + (size_t)tid * 3;
    float x = p[0], y = p[1], z = p[2];
    float p2 = x * x + y * y + z * z;
    pts4[tid] = make_float4(x, y, z, p2);
  }
  Wb[tid] = f2bf(W[tid]);                     // 512*128 = 65536 elements
}

// ---------------------------------------------------------------------------
// Stage A+B (r5-verified structure, 94us): per-wave kNN (QW queries/wave) +
// inverse-distance interp. Pass 1: per-lane min d2; tau = 10th-smallest
// lane-min (knockout); theta = tau+1ulp. Pass 2: tau-filtered distributed
// insert (lanes 0..9 hold sorted top-10 as u64 (d2|idx)). Output: bf16
// A[q][128] row-major (one packed dword per lane).
// ---------------------------------------------------------------------------
__global__ __launch_bounds__(256) void knn_interp_kernel(
    const float* __restrict__ geometry, const float4* __restrict__ pts4,
    const float* __restrict__ features, ushort_t* __restrict__ Abf)
{
  const int lane = threadIdx.x & 63;
  const int wave = (blockIdx.x << 2) | (threadIdx.x >> 6);
  const int q0   = wave * QW;           // QW consecutive queries (same batch)
  const int b    = q0 >> 13;            // q0 / 8192
  const float4* __restrict__ P = pts4 + ((size_t)b << 13);

  float m2x[QW], m2y[QW], m2z[QW], q2[QW];
#pragma unroll
  for (int j = 0; j < QW; ++j) {
    const float* g = geometry + (size_t)(q0 + j) * 3;
    float x = g[0], y = g[1], z = g[2];
    q2[j]  = x * x + y * y + z * z;
    m2x[j] = -2.0f * x; m2y[j] = -2.0f * y; m2z[j] = -2.0f * z;
  }

  // ---- pass 1: per-lane min (unclamped) ----
  float lmin[QW];
#pragma unroll
  for (int j = 0; j < QW; ++j) lmin[j] = INFINITY;
#pragma unroll 2
  for (int t = 0; t < NP / 64; ++t) {
    const float4 p = P[(t << 6) | lane];
#pragma unroll
    for (int j = 0; j < QW; ++j)
      lmin[j] = fminf(lmin[j], dist2m(m2x[j], m2y[j], m2z[j], q2[j], p));
  }
#pragma unroll
  for (int j = 0; j < QW; ++j) lmin[j] = fmaxf(lmin[j], 0.0f);  // clamp once

  // ---- tau = 10th-smallest lane-min (with multiplicity); theta = tau+1ulp --
  float theta[QW];
#pragma unroll
  for (int j = 0; j < QW; ++j) {
    float lm  = lmin[j];
    float tau = 0.0f;
#pragma unroll
    for (int r = 0; r < KNN; ++r) {
      tau = wmin64f(lm);
      u64 mk = __ballot(lm == tau);
      int w  = __builtin_ctzll(mk);
      if (lane == w) lm = INFINITY;
    }
    theta[j] = __uint_as_float(__float_as_uint(tau) + 1);  // include d2 == tau
  }

  u64   list[QW];
  float dl[QW];
#pragma unroll
  for (int j = 0; j < QW; ++j) {
    list[j] = 0x7F800000FFFFFFFFull;    // (+inf d2, idx=~0)
    dl[j]   = INFINITY;
  }
  const float qnan = __builtin_nanf("");

  // ---- pass 2: exact filtered insert ----
  for (int t = 0; t < NP / 64; ++t) {
    const float4 p = P[(t << 6) | lane];
#pragma unroll
    for (int j = 0; j < QW; ++j) {
      float d2 = dist2m(m2x[j], m2y[j], m2z[j], q2[j], p);
      // unclamped d2 vs theta(>=0): negative d2 still ballots true (correct)
      for (;;) {
        u64 mask = __ballot(d2 < theta[j]);
        if (!mask) break;
        int src = __builtin_ctzll(mask);
        float cd = __uint_as_float(
            (unsigned)__builtin_amdgcn_readlane(__float_as_int(d2), src));
        cd = fmaxf(cd, 0.0f);           // clamp candidate (matches reference)
        u64 kk = ((u64)__float_as_uint(cd) << 32) | (unsigned)((t << 6) + src);
        u64   prev  = shflup64(list[j]);
        float prevd = __shfl(dl[j], lane - 1, 64);  // shfl_up by 1
        bool mylt = list[j] < kk;
        bool pins = (lane == 0) || (prev < kk);
        list[j] = mylt ? list[j] : (pins ? kk : prev);
        dl[j]   = mylt ? dl[j]  : (pins ? cd : prevd);
        // min(): while list is underfull dl[9]=INF must not lift theta
        theta[j] = fminf(theta[j], __uint_as_float(
            (unsigned)__builtin_amdgcn_readlane(__float_as_int(dl[j]), 9)));
        if (lane == src) d2 = qnan;     // processed: exits all future ballots
      }
    }
  }

  // ---- weights + feature interpolation; bf16 row-major output ----
  const float* __restrict__ F = features + (size_t)b * NP * NF;
#pragma unroll
  for (int j = 0; j < QW; ++j) {
    float w = 1.0f / (sqrtf(dl[j]) + 1e-8f);      // meaningful on lanes 0..9
    float wsum = 0.0f;
#pragma unroll
    for (int jj = 0; jj < KNN; ++jj) wsum += __shfl(w, jj, 64);

    float a0 = 0.0f, a1 = 0.0f;
#pragma unroll
    for (int jj = 0; jj < KNN; ++jj) {
      float wj = __shfl(w, jj, 64) / wsum;
      int  mi  = (int)(unsigned)(shfl64(list[j], jj) & 0xffffffffull);
      const float2 f2 = *(const float2*)(F + (size_t)mi * NF + (lane << 1));
      a0 = fmaf(wj, f2.x, a0);
      a1 = fmaf(wj, f2.y, a1);
    }
    unsigned pack = (unsigned)f2bf(a0) | ((unsigned)f2bf(a1) << 16);
    *(unsigned*)(Abf + (size_t)(q0 + j) * NF + (lane << 1)) = pack;
  }
}

// ---------------------------------------------------------------------------
// Stage C (MFMA): out[q][o] = sum_f A[q][f] * Wb[o][f] + bias[o]
// 16x16x32 bf16 MFMA. Block = 4 waves, tile M=128 x N=64; per wave 64x32
// (4 m-frags x 2 n-frags), K-loop 4 steps of 32. Direct global fragment
// loads (A 4MB + W 128KB are L2-resident).
// Fragment maps (guide §3, m89-verified): A row=lane&15, k=(lane>>4)*8+e;
// B col=lane&15, k=(lane>>4)*8+e; C col=lane&15, row=(lane>>4)*4+reg.
// ---------------------------------------------------------------------------
__global__ __launch_bounds__(256) void proj_mfma(
    const ushort_t* __restrict__ Abf, const ushort_t* __restrict__ Wb,
    const float* __restrict__ bias, float* __restrict__ out)
{
  const int lane = threadIdx.x & 63;
  const int w    = threadIdx.x >> 6;        // wave 0..3
  const int mt   = blockIdx.x & 127;        // 128 m-blocks
  const int ot   = blockIdx.x >> 7;         // 8 o-blocks
  const int m0   = (mt << 7) + ((w & 1) << 6);   // wave's 64-row band
  const int o0   = (ot << 6) + ((w >> 1) << 5);  // wave's 32-col band
  const int r    = lane & 15;
  const int kg   = (lane >> 4) << 3;        // k offset 0,8,16,24

  f32x4 acc[4][2];
#pragma unroll
  for (int i = 0; i < 4; ++i)
#pragma unroll
    for (int jn = 0; jn < 2; ++jn) acc[i][jn] = (f32x4)0.0f;

#pragma unroll
  for (int ks = 0; ks < 4; ++ks) {
    const int k0 = (ks << 5) + kg;
    bf16x8 a[4], bb[2];
#pragma unroll
    for (int i = 0; i < 4; ++i)
      a[i] = *(const bf16x8*)(Abf + (size_t)(m0 + (i << 4) + r) * NF + k0);
#pragma unroll
    for (int jn = 0; jn < 2; ++jn)
      bb[jn] = *(const bf16x8*)(Wb + (size_t)(o0 + (jn << 4) + r) * NF + k0);
#pragma unroll
    for (int i = 0; i < 4; ++i)
#pragma unroll
      for (int jn = 0; jn < 2; ++jn)
        acc[i][jn] = __builtin_amdgcn_mfma_f32_16x16x32_bf16(
            a[i], bb[jn], acc[i][jn], 0, 0, 0);
  }

  const int crow = (lane >> 4) << 2;
#pragma unroll
  for (int jn = 0; jn < 2; ++jn) {
    const int oc = o0 + (jn << 4) + r;
    const float bv = bias[oc];
#pragma unroll
    for (int i = 0; i < 4; ++i) {
#pragma unroll
      for (int reg = 0; reg < 4; ++reg) {
        const int qm = m0 + (i << 4) + crow + reg;
        out[(size_t)qm * NOUT + oc] = acc[i][jn][reg] + bv;
      }
    }
  }
}

// ---------------------------------------------------------------------------
extern "C" void kernel_launch(void* const* d_in, const int* in_sizes, int n_in,
                              void* d_out, int out_size, void* d_ws, size_t ws_size,
                              hipStream_t stream) {
  const float* geometry = (const float*)d_in[0];   // [2,8192,3]
  const float* gpcd     = (const float*)d_in[1];   // [2,8192,3]
  const float* features = (const float*)d_in[2];   // [2,8192,128]
  const float* W        = (const float*)d_in[3];   // [512,128]
  const float* bias     = (const float*)d_in[4];   // [512]
  float* out = (float*)d_out;

  // workspace: Abf 4 MiB | pts4 256 KiB | Wb 128 KiB
  char*     ws   = (char*)d_ws;
  ushort_t* Abf  = (ushort_t*)ws;
  float4*   pts4 = (float4*)(ws + (size_t)BNQ * NF * 2);
  ushort_t* Wb   = (ushort_t*)(ws + (size_t)BNQ * NF * 2 + (size_t)NB * NP * 16);

  prep_kernel<<<256, 256, 0, stream>>>(gpcd, W, pts4, Wb);
  knn_interp_kernel<<<BNQ / (QW * 4), 256, 0, stream>>>(geometry, pts4, features, Abf);
  proj_mfma<<<(BNQ / 128) * (NOUT / 64), 256, 0, stream>>>(Abf, Wb, bias, out);
}

// Round 10
// 112.347 us; speedup vs baseline: 1.6137x; 1.0143x over previous
//
#include <hip/hip_runtime.h>
#include <math.h>

#define NQ   8192      // N queries per batch
#define NP   8192      // M points per batch
#define NF   128       // feature dim
#define NOUT 512       // output dim
#define NB   2         // batches
#define KNN  10
#define BNQ  (NB*NQ)   // 16384 total queries
#define QW   2         // queries per wave (32 waves/CU occupancy)

typedef unsigned long long u64;
typedef unsigned short ushort_t;
typedef __attribute__((ext_vector_type(8))) short bf16x8;
typedef __attribute__((ext_vector_type(4))) float f32x4;

__device__ __forceinline__ u64 shfl64(u64 v, int src) {
  unsigned lo = (unsigned)__shfl((int)(unsigned)(v & 0xffffffffull), src, 64);
  unsigned hi = (unsigned)__shfl((int)(unsigned)(v >> 32), src, 64);
  return ((u64)hi << 32) | lo;
}
__device__ __forceinline__ u64 shflup64(u64 v) {
  unsigned lo = (unsigned)__shfl_up((int)(unsigned)(v & 0xffffffffull), 1, 64);
  unsigned hi = (unsigned)__shfl_up((int)(unsigned)(v >> 32), 1, 64);
  return ((u64)hi << 32) | lo;
}

// Shifted distance for SELECTION: d2' = p2 - 2 q.p  (3 fma). True d2 = d2'+q2.
// Order w.r.t. a fixed query is preserved (q2 is a per-query constant).
__device__ __forceinline__ float dist2s(float m2x, float m2y, float m2z,
                                        float4 p) {
  return fmaf(m2x, p.x, fmaf(m2y, p.y, fmaf(m2z, p.z, p.w)));
}

// Monotone f32->u32 bit map: mono(a) < mono(b) (unsigned) <=> a < b (float).
__device__ __forceinline__ unsigned fmono(float f) {
  unsigned u = __float_as_uint(f);
  return u ^ ((unsigned)((int)u >> 31) | 0x80000000u);
}

// nextafter(f, +inf) for finite f incl. negatives and -0 (r7-verified).
__device__ __forceinline__ float nextupf(float f) {
  unsigned u = __float_as_uint(f);
  unsigned n = (u & 0x80000000u) ? ((u == 0x80000000u) ? 1u : u - 1u) : u + 1u;
  return __uint_as_float(n);
}

__device__ __forceinline__ float wmin64f(float v) {
#pragma unroll
  for (int off = 1; off < 64; off <<= 1)
    v = fminf(v, __shfl_xor(v, off, 64));
  return v;   // broadcast min across all 64 lanes
}

// round-to-nearest-even f32 -> bf16
__device__ __forceinline__ ushort_t f2bf(float x) {
  unsigned u = __float_as_uint(x);
  return (ushort_t)((u + 0x7FFFu + ((u >> 16) & 1u)) >> 16);
}

// ---------------------------------------------------------------------------
// Prep: pack points as (x,y,z,|p|^2); convert W[512][128] -> bf16 Wb[512][128]
// ---------------------------------------------------------------------------
__global__ __launch_bounds__(256) void prep_kernel(
    const float* __restrict__ gpcd, const float* __restrict__ W,
    float4* __restrict__ pts4, ushort_t* __restrict__ Wb)
{
  int tid = blockIdx.x * 256 + threadIdx.x;   // 0..65535
  if (tid < NB * NP) {
    const float* p = gpcd + (size_t)tid * 3;
    float x = p[0], y = p[1], z = p[2];
    float p2 = x * x + y * y + z * z;
    pts4[tid] = make_float4(x, y, z, p2);
  }
  Wb[tid] = f2bf(W[tid]);                     // 512*128 = 65536 elements
}

// ---------------------------------------------------------------------------
// Stage A+B (r5-verified structure; QW=2, shifted distance):
// Pass 1: per-lane min of d2' over its 128 points. tau = 10th-smallest
// lane-min (knockout); theta = nextup(tau) (includes ties at tau).
// Pass 2: tau-filtered distributed insert, ascending index order, strict <
// (exact lax.top_k tie-breaks). Keys: (mono(d2')<<32)|idx. Output: bf16
// A[q][128] row-major.
// ---------------------------------------------------------------------------
__global__ __launch_bounds__(256) void knn_interp_kernel(
    const float* __restrict__ geometry, const float4* __restrict__ pts4,
    const float* __restrict__ features, ushort_t* __restrict__ Abf)
{
  const int lane = threadIdx.x & 63;
  const int wave = (blockIdx.x << 2) | (threadIdx.x >> 6);
  const int q0   = wave * QW;           // QW consecutive queries (same batch)
  const int b    = q0 >> 13;            // q0 / 8192
  const float4* __restrict__ P = pts4 + ((size_t)b << 13);

  float m2x[QW], m2y[QW], m2z[QW], q2[QW];
#pragma unroll
  for (int j = 0; j < QW; ++j) {
    const float* g = geometry + (size_t)(q0 + j) * 3;
    float x = g[0], y = g[1], z = g[2];
    q2[j]  = x * x + y * y + z * z;
    m2x[j] = -2.0f * x; m2y[j] = -2.0f * y; m2z[j] = -2.0f * z;
  }

  // ---- pass 1: per-lane min of shifted d2' ----
  float lmin[QW];
#pragma unroll
  for (int j = 0; j < QW; ++j) lmin[j] = INFINITY;
#pragma unroll 2
  for (int t = 0; t < NP / 64; ++t) {
    const float4 p = P[(t << 6) | lane];
#pragma unroll
    for (int j = 0; j < QW; ++j)
      lmin[j] = fminf(lmin[j], dist2s(m2x[j], m2y[j], m2z[j], p));
  }

  // ---- tau = 10th-smallest lane-min; theta = nextup(tau) ----
  float theta[QW];
#pragma unroll
  for (int j = 0; j < QW; ++j) {
    float lm  = lmin[j];
    float tau = 0.0f;
#pragma unroll
    for (int r = 0; r < KNN; ++r) {
      tau = wmin64f(lm);
      u64 mk = __ballot(lm == tau);
      int w  = __builtin_ctzll(mk);
      if (lane == w) lm = INFINITY;
    }
    theta[j] = nextupf(tau);            // include d2' == tau
  }

  u64   list[QW];
  float dl[QW];
#pragma unroll
  for (int j = 0; j < QW; ++j) {
    list[j] = 0xFFFFFFFFFFFFFFFFull;    // maximal key
    dl[j]   = INFINITY;
  }
  const float qnan = __builtin_nanf("");

  // ---- pass 2: exact filtered insert (ascending index order) ----
  for (int t = 0; t < NP / 64; ++t) {
    const float4 p = P[(t << 6) | lane];
#pragma unroll
    for (int j = 0; j < QW; ++j) {
      float d2 = dist2s(m2x[j], m2y[j], m2z[j], p);
      for (;;) {
        u64 mask = __ballot(d2 < theta[j]);
        if (!mask) break;
        int src = __builtin_ctzll(mask);
        float cd = __uint_as_float(
            (unsigned)__builtin_amdgcn_readlane(__float_as_int(d2), src));
        u64 kk = ((u64)fmono(cd) << 32) | (unsigned)((t << 6) + src);
        u64   prev  = shflup64(list[j]);
        float prevd = __shfl(dl[j], lane - 1, 64);  // shfl_up by 1
        bool mylt = list[j] < kk;
        bool pins = (lane == 0) || (prev < kk);
        list[j] = mylt ? list[j] : (pins ? kk : prev);
        dl[j]   = mylt ? dl[j]  : (pins ? cd : prevd);
        // ascending-index processing: strict < vs raw dl[9] is exact;
        // min() so an underfull list (dl9=INF) can't lift theta
        theta[j] = fminf(theta[j], __uint_as_float(
            (unsigned)__builtin_amdgcn_readlane(__float_as_int(dl[j]), 9)));
        if (lane == src) d2 = qnan;     // processed: exits all future ballots
      }
    }
  }

  // ---- weights + feature interpolation; bf16 row-major output ----
  const float* __restrict__ F = features + (size_t)b * NP * NF;
#pragma unroll
  for (int j = 0; j < QW; ++j) {
    float td2 = fmaxf(dl[j] + q2[j], 0.0f);       // back to true d2, clamped
    float w   = 1.0f / (sqrtf(td2) + 1e-8f);      // meaningful on lanes 0..9
    float wsum = 0.0f;
#pragma unroll
    for (int jj = 0; jj < KNN; ++jj) wsum += __shfl(w, jj, 64);

    float a0 = 0.0f, a1 = 0.0f;
#pragma unroll
    for (int jj = 0; jj < KNN; ++jj) {
      float wj = __shfl(w, jj, 64) / wsum;
      int  mi  = (int)(unsigned)(shfl64(list[j], jj) & 0xffffffffull);
      const float2 f2 = *(const float2*)(F + (size_t)mi * NF + (lane << 1));
      a0 = fmaf(wj, f2.x, a0);
      a1 = fmaf(wj, f2.y, a1);
    }
    unsigned pack = (unsigned)f2bf(a0) | ((unsigned)f2bf(a1) << 16);
    *(unsigned*)(Abf + (size_t)(q0 + j) * NF + (lane << 1)) = pack;
  }
}

// ---------------------------------------------------------------------------
// Stage C (MFMA, r9-verified): out[q][o] = sum_f A[q][f]*Wb[o][f] + bias[o]
// 16x16x32 bf16 MFMA. Block = 4 waves, tile M=128 x N=64; per wave 64x32.
// ---------------------------------------------------------------------------
__global__ __launch_bounds__(256) void proj_mfma(
    const ushort_t* __restrict__ Abf, const ushort_t* __restrict__ Wb,
    const float* __restrict__ bias, float* __restrict__ out)
{
  const int lane = threadIdx.x & 63;
  const int w    = threadIdx.x >> 6;        // wave 0..3
  const int mt   = blockIdx.x & 127;        // 128 m-blocks
  const int ot   = blockIdx.x >> 7;         // 8 o-blocks
  const int m0   = (mt << 7) + ((w & 1) << 6);   // wave's 64-row band
  const int o0   = (ot << 6) + ((w >> 1) << 5);  // wave's 32-col band
  const int r    = lane & 15;
  const int kg   = (lane >> 4) << 3;        // k offset 0,8,16,24

  f32x4 acc[4][2];
#pragma unroll
  for (int i = 0; i < 4; ++i)
#pragma unroll
    for (int jn = 0; jn < 2; ++jn) acc[i][jn] = (f32x4)0.0f;

#pragma unroll
  for (int ks = 0; ks < 4; ++ks) {
    const int k0 = (ks << 5) + kg;
    bf16x8 a[4], bb[2];
#pragma unroll
    for (int i = 0; i < 4; ++i)
      a[i] = *(const bf16x8*)(Abf + (size_t)(m0 + (i << 4) + r) * NF + k0);
#pragma unroll
    for (int jn = 0; jn < 2; ++jn)
      bb[jn] = *(const bf16x8*)(Wb + (size_t)(o0 + (jn << 4) + r) * NF + k0);
#pragma unroll
    for (int i = 0; i < 4; ++i)
#pragma unroll
      for (int jn = 0; jn < 2; ++jn)
        acc[i][jn] = __builtin_amdgcn_mfma_f32_16x16x32_bf16(
            a[i], bb[jn], acc[i][jn], 0, 0, 0);
  }

  const int crow = (lane >> 4) << 2;
#pragma unroll
  for (int jn = 0; jn < 2; ++jn) {
    const int oc = o0 + (jn << 4) + r;
    const float bv = bias[oc];
#pragma unroll
    for (int i = 0; i < 4; ++i) {
#pragma unroll
      for (int reg = 0; reg < 4; ++reg) {
        const int qm = m0 + (i << 4) + crow + reg;
        out[(size_t)qm * NOUT + oc] = acc[i][jn][reg] + bv;
      }
    }
  }
}

// ---------------------------------------------------------------------------
extern "C" void kernel_launch(void* const* d_in, const int* in_sizes, int n_in,
                              void* d_out, int out_size, void* d_ws, size_t ws_size,
                              hipStream_t stream) {
  const float* geometry = (const float*)d_in[0];   // [2,8192,3]
  const float* gpcd     = (const float*)d_in[1];   // [2,8192,3]
  const float* features = (const float*)d_in[2];   // [2,8192,128]
  const float* W        = (const float*)d_in[3];   // [512,128]
  const float* bias     = (const float*)d_in[4];   // [512]
  float* out = (float*)d_out;

  // workspace: Abf 4 MiB | pts4 256 KiB | Wb 128 KiB
  char*     ws   = (char*)d_ws;
  ushort_t* Abf  = (ushort_t*)ws;
  float4*   pts4 = (float4*)(ws + (size_t)BNQ * NF * 2);
  ushort_t* Wb   = (ushort_t*)(ws + (size_t)BNQ * NF * 2 + (size_t)NB * NP * 16);

  prep_kernel<<<256, 256, 0, stream>>>(gpcd, W, pts4, Wb);
  knn_interp_kernel<<<BNQ / (QW * 4), 256, 0, stream>>>(geometry, pts4, features, Abf);
  proj_mfma<<<(BNQ / 128) * (NOUT / 64), 256, 0, stream>>>(Abf, Wb, bias, out);
}